// Round 4
// baseline (193.164 us; speedup 1.0000x reference)
//
#include <hip/hip_runtime.h>
#include <math.h>

#define NCLS 80
#define NA 8400
#define NB 32
#define NO 144
#define PRE_TOPK 1000
#define MAX_DET 100
#define CHUNK 125

// ---------------- Kernel 1: decode (DFL + max-logit sigmoid) ----------------
// One thread per (batch, anchor). Grouped loads (16-20 in flight) keep VGPR
// pressure low (no spill) while preserving memory-level parallelism.
template<int HW, int WDIM, int S>
__device__ __forceinline__ void decode_store(
    const float* __restrict__ src, int g, int aoff,
    float* __restrict__ conf, int* __restrict__ clsid, float* __restrict__ box)
{
    int b = g / HW;
    int pos = g - b * HW;
    float ax = (float)(pos % WDIM) + 0.5f;
    float ay = (float)(pos / WDIM) + 0.5f;
    const float* base = src + (size_t)b * (NO * HW) + pos;

    // DFL: softmax over 16 bins per side, dot with arange(16)
    float dist[4];
    #pragma unroll
    for (int s4 = 0; s4 < 4; ++s4) {
        float v[16];
        #pragma unroll
        for (int r = 0; r < 16; ++r) v[r] = base[(size_t)(s4 * 16 + r) * HW];
        float mm = v[0];
        #pragma unroll
        for (int r = 1; r < 16; ++r) mm = fmaxf(mm, v[r]);
        float sum = 0.f;
        #pragma unroll
        for (int r = 0; r < 16; ++r) { v[r] = __expf(v[r] - mm); sum += v[r]; }
        float inv = 1.0f / sum;
        float d = 0.f;
        #pragma unroll
        for (int r = 1; r < 16; ++r) d += (v[r] * inv) * (float)r;
        dist[s4] = d;
    }

    // class argmax over logits in 4 chunks of 20 (first-occurrence ties),
    // then one sigmoid (sigmoid is monotone: max(sigmoid)==sigmoid(max)).
    float best = -INFINITY; int bid = 0;
    #pragma unroll
    for (int ch = 0; ch < 4; ++ch) {
        float vc[20];
        #pragma unroll
        for (int c = 0; c < 20; ++c) vc[c] = base[(size_t)(64 + ch * 20 + c) * HW];
        float m = vc[0]; int ii = 0;
        #pragma unroll
        for (int c = 1; c < 20; ++c) if (vc[c] > m) { m = vc[c]; ii = c; }
        if (m > best) { best = m; bid = ch * 20 + ii; }
    }
    float conf_v = 1.0f / (1.0f + __expf(-best));

    float x1 = ax - dist[0], y1 = ay - dist[1];
    float x2 = ax + dist[2], y2 = ay + dist[3];
    float cx = ((x1 + x2) * 0.5f) * (float)S;
    float cy = ((y1 + y2) * 0.5f) * (float)S;
    float w  = (x2 - x1) * (float)S;
    float h  = (y2 - y1) * (float)S;

    size_t gid = (size_t)b * NA + aoff + pos;
    conf[gid]  = conf_v;
    clsid[gid] = bid;
    *(float4*)(box + gid * 4) = make_float4(cx, cy, w, h);
}

__global__ __launch_bounds__(256) void k_decode(
    const float* __restrict__ p3, const float* __restrict__ p4, const float* __restrict__ p5,
    float* __restrict__ conf, int* __restrict__ clsid, float* __restrict__ box)
{
    int blk = blockIdx.x;
    int t = threadIdx.x;
    if (blk < 800) {            // p3: 32 * 6400 threads
        int g = blk * 256 + t;
        decode_store<6400, 80, 8>(p3, g, 0, conf, clsid, box);
    } else if (blk < 1000) {    // p4: 32 * 1600 threads
        int g = (blk - 800) * 256 + t;
        decode_store<1600, 40, 16>(p4, g, 6400, conf, clsid, box);
    } else {                    // p5: 32 * 400 threads
        int g = (blk - 1000) * 256 + t;
        decode_store<400, 20, 32>(p5, g, 8000, conf, clsid, box);
    }
}

// ---------------- Kernel 2: fused top-1000 + IoU + NMS + emit ----------------
// One block per batch. Phased LDS layout (~46 KB):
//   phase A (select+sort): ob[8400] @0 (33600B), hist @36608 (1024B), sbuf @37632 (8192B)
//   phase B (iou+nms):     boxes @0 (16000B), sv @16000 (4000B),
//                          mrows @20000 (16000B), kept @36000 (400B); sbuf persists
#define SM_SV    16000
#define SM_MROWS 20000
#define SM_KEPT  36000
#define SM_HIST  36608
#define SM_SBUF  37632
#define SM_SIZE  45824

__device__ __forceinline__ uint32_t ord_bits(float f) {
    uint32_t u = __float_as_uint(f);
    return (u & 0x80000000u) ? ~u : (u | 0x80000000u);
}

__global__ __launch_bounds__(1024) void k_post(
    const float* __restrict__ conf, const float* __restrict__ box, const int* __restrict__ clsid,
    float* __restrict__ out)
{
    int b = blockIdx.x;
    int t = threadIdx.x;

    __shared__ __align__(16) char smem[SM_SIZE];
    __shared__ uint64_t s_prefix;
    __shared__ int s_k;
    __shared__ int s_cnt;
    __shared__ int s_done;
    __shared__ unsigned long long s_supp[16];

    uint32_t* ob   = (uint32_t*)smem;
    uint32_t* hist = (uint32_t*)(smem + SM_HIST);
    uint64_t* sbuf = (uint64_t*)(smem + SM_SBUF);

    // ---- phase A: thresholded ordered keys ----
    const float* cf = conf + (size_t)b * NA;
    for (int i = t; i < NA; i += 1024) {
        float c = cf[i];
        float cm = (c > 0.25f) ? c : -1.0f;
        ob[i] = ord_bits(cm);
    }
    if (t == 0) { s_prefix = 0; s_k = PRE_TOPK; s_cnt = 0; s_done = 0; }
    if (t < 16) s_supp[t] = 0;
    sbuf[t] = 0;
    __syncthreads();

    // radix-select exact rank-1000 key (keys unique: index embedded)
    for (int pass = 0; pass < 8; ++pass) {
        int shift = 56 - 8 * pass;
        if (t < 256) hist[t] = 0;
        __syncthreads();
        uint64_t prefix = s_prefix;
        int k = s_k;
        for (int i = t; i < NA; i += 1024) {
            uint64_t key = ((uint64_t)ob[i] << 32) | (uint64_t)(0xFFFFFFFFu - (uint32_t)i);
            bool match = (pass == 0) || (((key ^ prefix) >> (64 - 8 * pass)) == 0);
            if (match) atomicAdd(&hist[(uint32_t)(key >> shift) & 255u], 1u);
        }
        __syncthreads();
        if (t < 64) {   // wave-0 suffix-scan digit selection
            uint32_t h0 = hist[4 * t + 0], h1 = hist[4 * t + 1];
            uint32_t h2 = hist[4 * t + 2], h3 = hist[4 * t + 3];
            uint32_t part = h0 + h1 + h2 + h3;
            uint32_t s = part;
            #pragma unroll
            for (int off = 1; off < 64; off <<= 1) {
                uint32_t v = __shfl_down(s, off);
                if (t + off < 64) s += v;
            }
            uint32_t cb3 = s - part;
            uint32_t cb2 = cb3 + h3;
            uint32_t cb1 = cb2 + h2;
            uint32_t cb0 = cb1 + h1;
            uint32_t ku = (uint32_t)k;
            if (cb3 < ku && ku <= cb3 + h3) { s_k = k - (int)cb3; s_prefix = prefix | ((uint64_t)(uint32_t)(4 * t + 3) << shift); }
            if (cb2 < ku && ku <= cb2 + h2) { s_k = k - (int)cb2; s_prefix = prefix | ((uint64_t)(uint32_t)(4 * t + 2) << shift); }
            if (cb1 < ku && ku <= cb1 + h1) { s_k = k - (int)cb1; s_prefix = prefix | ((uint64_t)(uint32_t)(4 * t + 1) << shift); }
            if (cb0 < ku && ku <= cb0 + h0) { s_k = k - (int)cb0; s_prefix = prefix | ((uint64_t)(uint32_t)(4 * t + 0) << shift); }
        }
        __syncthreads();
    }

    // compact keys >= K* (exactly 1000 by key uniqueness)
    uint64_t kstar = s_prefix;
    for (int i = t; i < NA; i += 1024) {
        uint64_t key = ((uint64_t)ob[i] << 32) | (uint64_t)(0xFFFFFFFFu - (uint32_t)i);
        if (key >= kstar) {
            int p = atomicAdd(&s_cnt, 1);
            if (p < 1024) sbuf[p] = key;
        }
    }
    __syncthreads();
    // s_cnt served as the compaction cursor (==1000 here); the NMS walk needs
    // it back at 0. Reset before the sort — the sort's barriers order it.
    if (t == 0) s_cnt = 0;

    // bitonic sort 1024 descending by (conf, -index)
    for (int k = 2; k <= 1024; k <<= 1) {
        for (int j = k >> 1; j > 0; j >>= 1) {
            int ixj = t ^ j;
            if (ixj > t) {
                uint64_t A = sbuf[t], Bv = sbuf[ixj];
                bool descBlock = ((t & k) == 0);
                bool sw = descBlock ? (A < Bv) : (A > Bv);
                if (sw) { sbuf[t] = Bv; sbuf[ixj] = A; }
            }
            __syncthreads();
        }
    }
    // (last stage ends with a barrier; ob/hist are dead from here)

    // ---- phase B: boxes/scores to LDS ----
    float4* boxes = (float4*)smem;
    float*  sv    = (float*)(smem + SM_SV);
    uint64_t* mrows = (uint64_t*)(smem + SM_MROWS);
    int* kept = (int*)(smem + SM_KEPT);

    if (t < PRE_TOPK) {
        uint64_t key = sbuf[t];
        uint32_t u = (uint32_t)(key >> 32);
        uint32_t fb = (u & 0x80000000u) ? (u ^ 0x80000000u) : ~u;
        sv[t] = __uint_as_float(fb);
        int idx = (int)(0xFFFFFFFFu - (uint32_t)(key & 0xFFFFFFFFull));
        size_t g = (size_t)b * NA + idx;
        float4 bx = *(const float4*)(box + g * 4);
        float cx = bx.x, cy = bx.y, w = bx.z, h = bx.w;
        boxes[t] = make_float4(cx - w * 0.5f, cy - h * 0.5f, cx + w * 0.5f, cy + h * 0.5f);
    }
    __syncthreads();

    // ---- chunked IoU-mask + sequential walk, early-exit at 100 keeps ----
    for (int c = 0; c < 8; ++c) {
        int base = c * CHUNK;
        // compute this chunk's mask rows (2000 tasks of 64 IoUs)
        for (int tt = t; tt < CHUNK * 16; tt += 1024) {
            int rl = tt >> 4, w = tt & 15;
            int row = base + rl;
            unsigned long long bits = 0;
            float4 bi = boxes[row];
            float area_i = (bi.z - bi.x) * (bi.w - bi.y);
            int j0 = w * 64;
            #pragma unroll 4
            for (int jj = 0; jj < 64; ++jj) {
                int j = j0 + jj;
                if (j >= PRE_TOPK) break;
                if (j <= row) continue;
                float4 bj = boxes[j];
                float lx = fmaxf(bi.x, bj.x), ly = fmaxf(bi.y, bj.y);
                float rx = fminf(bi.z, bj.z), ry = fminf(bi.w, bj.w);
                float iw = fmaxf(rx - lx, 0.f), ih = fmaxf(ry - ly, 0.f);
                float inter = iw * ih;
                float area_j = (bj.z - bj.x) * (bj.w - bj.y);
                float iou = inter / (area_i + area_j - inter + 1e-7f);
                if (iou > 0.45f) bits |= (1ull << jj);
            }
            mrows[tt] = bits;
        }
        __syncthreads();
        if (t < 64) {  // wave-0 sequential walk
            unsigned long long supp = (t < 16) ? s_supp[t] : 0ull;
            int cnt = s_cnt;
            int end = base + CHUNK;
            for (int i = base; i < end; ++i) {
                int wsel = i >> 6, bit = i & 63;
                int sbit = (int)((supp >> bit) & 1ull);
                sbit = __shfl(sbit, wsel);
                bool keep = (!sbit) && (sv[i] > 0.0f);
                if (keep) {
                    if (t < 16) supp |= mrows[(i - base) * 16 + t];
                    if (t == 0 && cnt < MAX_DET) kept[cnt] = i;
                    ++cnt;
                }
            }
            if (t < 16) s_supp[t] = supp;
            if (t == 0) { s_cnt = cnt; if (cnt >= MAX_DET) s_done = 1; }
        }
        __syncthreads();
        if (s_done) break;   // uniform: written before the barrier
    }

    // ---- emit ----
    int cnt = s_cnt; if (cnt > MAX_DET) cnt = MAX_DET;
    if (t == 0) out[b] = (float)cnt;                       // num_dets (B,1)
    if (t < MAX_DET) {
        bool valid = t < cnt;
        float bx0 = 0.f, bx1 = 0.f, bx2 = 0.f, bx3 = 0.f, sc = 0.f, cl = 0.f;
        if (valid) {
            int p = kept[t];
            float4 bb = boxes[p];
            bx0 = bb.x; bx1 = bb.y; bx2 = bb.z; bx3 = bb.w;
            sc = sv[p];
            uint64_t key = sbuf[p];
            int idx = (int)(0xFFFFFFFFu - (uint32_t)(key & 0xFFFFFFFFull));
            cl = (float)clsid[(size_t)b * NA + idx];
        }
        size_t db = 32 + ((size_t)b * MAX_DET + t) * 4;
        out[db + 0] = bx0; out[db + 1] = bx1; out[db + 2] = bx2; out[db + 3] = bx3;
        out[32 + 12800 + (size_t)b * MAX_DET + t] = sc;    // det_scores
        out[32 + 16000 + (size_t)b * MAX_DET + t] = cl;    // det_classes
    }
}

// ---------------- launch ----------------
extern "C" void kernel_launch(void* const* d_in, const int* in_sizes, int n_in,
                              void* d_out, int out_size, void* d_ws, size_t ws_size,
                              hipStream_t stream)
{
    const float* p3 = (const float*)d_in[0];
    const float* p4 = (const float*)d_in[1];
    const float* p5 = (const float*)d_in[2];
    float* out = (float*)d_out;

    char* ws = (char*)d_ws;
    size_t off_conf = 0;
    size_t off_cls  = off_conf + (size_t)NB * NA * 4;
    size_t off_box  = off_cls  + (size_t)NB * NA * 4;        // 16B-aligned

    float* conf  = (float*)(ws + off_conf);
    int*   clsid = (int*)(ws + off_cls);
    float* box   = (float*)(ws + off_box);

    k_decode<<<1050, 256, 0, stream>>>(p3, p4, p5, conf, clsid, box);
    k_post<<<NB, 1024, 0, stream>>>(conf, box, clsid, out);
}

// Round 5
// 173.102 us; speedup vs baseline: 1.1159x; 1.1159x over previous
//
#include <hip/hip_runtime.h>
#include <math.h>

#define NCLS 80
#define NA 8400
#define NB 32
#define NO 144
#define PRE_TOPK 1000
#define MAX_DET 100
#define CHUNK 125

// ---------------- Kernel 1: decode (DFL + max-logit sigmoid) ----------------
template<int HW, int WDIM, int S>
__device__ __forceinline__ void decode_store(
    const float* __restrict__ src, int g, int aoff,
    float* __restrict__ conf, int* __restrict__ clsid, float* __restrict__ box)
{
    int b = g / HW;
    int pos = g - b * HW;
    float ax = (float)(pos % WDIM) + 0.5f;
    float ay = (float)(pos / WDIM) + 0.5f;
    const float* base = src + (size_t)b * (NO * HW) + pos;

    // DFL: softmax over 16 bins per side, dot with arange(16)
    float dist[4];
    #pragma unroll
    for (int s4 = 0; s4 < 4; ++s4) {
        float v[16];
        #pragma unroll
        for (int r = 0; r < 16; ++r) v[r] = base[(size_t)(s4 * 16 + r) * HW];
        float mm = v[0];
        #pragma unroll
        for (int r = 1; r < 16; ++r) mm = fmaxf(mm, v[r]);
        float sum = 0.f;
        #pragma unroll
        for (int r = 0; r < 16; ++r) { v[r] = __expf(v[r] - mm); sum += v[r]; }
        float inv = 1.0f / sum;
        float d = 0.f;
        #pragma unroll
        for (int r = 1; r < 16; ++r) d += (v[r] * inv) * (float)r;
        dist[s4] = d;
    }

    // class argmax over logits (monotone sigmoid -> sigmoid(max)), 4 chunks of 20
    float best = -INFINITY; int bid = 0;
    #pragma unroll
    for (int ch = 0; ch < 4; ++ch) {
        float vc[20];
        #pragma unroll
        for (int c = 0; c < 20; ++c) vc[c] = base[(size_t)(64 + ch * 20 + c) * HW];
        float m = vc[0]; int ii = 0;
        #pragma unroll
        for (int c = 1; c < 20; ++c) if (vc[c] > m) { m = vc[c]; ii = c; }
        if (m > best) { best = m; bid = ch * 20 + ii; }
    }
    float conf_v = 1.0f / (1.0f + __expf(-best));

    float x1 = ax - dist[0], y1 = ay - dist[1];
    float x2 = ax + dist[2], y2 = ay + dist[3];
    float cx = ((x1 + x2) * 0.5f) * (float)S;
    float cy = ((y1 + y2) * 0.5f) * (float)S;
    float w  = (x2 - x1) * (float)S;
    float h  = (y2 - y1) * (float)S;

    size_t gid = (size_t)b * NA + aoff + pos;
    conf[gid]  = conf_v;
    clsid[gid] = bid;
    *(float4*)(box + gid * 4) = make_float4(cx, cy, w, h);
}

__global__ __launch_bounds__(256) void k_decode(
    const float* __restrict__ p3, const float* __restrict__ p4, const float* __restrict__ p5,
    float* __restrict__ conf, int* __restrict__ clsid, float* __restrict__ box)
{
    int blk = blockIdx.x;
    int t = threadIdx.x;
    if (blk < 800) {
        int g = blk * 256 + t;
        decode_store<6400, 80, 8>(p3, g, 0, conf, clsid, box);
    } else if (blk < 1000) {
        int g = (blk - 800) * 256 + t;
        decode_store<1600, 40, 16>(p4, g, 6400, conf, clsid, box);
    } else {
        int g = (blk - 1000) * 256 + t;
        decode_store<400, 20, 32>(p5, g, 8000, conf, clsid, box);
    }
}

// ---------------- Kernel 2: fused top-1000 + IoU + NMS + emit ----------------
// Phased LDS layout:
//   phase A: ob[8400] @0 (33600B) | hist @36656 | sbuf @37680 (persists)
//   phase B: boxes(padded) @0 (16256B), sv @16256, mrows @20256, kept @36256
// boxes are stored PADDED: slot(j) = j + (j>>6). The IoU inner loop's lane
// stride becomes 65 float4 (1040B) -> bank offset 4/lane -> 2-way conflict
// (free, m136) instead of 16-way at stride 64 (1024B, all lanes same bank).
#define SM_SV    16256
#define SM_MROWS 20256
#define SM_KEPT  36256
#define SM_HIST  36656
#define SM_SBUF  37680
#define SM_SIZE  45872

__device__ __forceinline__ int bslot(int j) { return j + (j >> 6); }

__device__ __forceinline__ uint32_t ord_bits(float f) {
    uint32_t u = __float_as_uint(f);
    return (u & 0x80000000u) ? ~u : (u | 0x80000000u);
}

__global__ __launch_bounds__(1024) void k_post(
    const float* __restrict__ conf, const float* __restrict__ box, const int* __restrict__ clsid,
    float* __restrict__ out)
{
    int b = blockIdx.x;
    int t = threadIdx.x;

    __shared__ __align__(16) char smem[SM_SIZE];
    __shared__ uint64_t s_prefix;
    __shared__ int s_k;
    __shared__ int s_cnt;
    __shared__ int s_done;
    __shared__ unsigned long long s_supp[16];

    uint32_t* ob   = (uint32_t*)smem;
    uint32_t* hist = (uint32_t*)(smem + SM_HIST);
    uint64_t* sbuf = (uint64_t*)(smem + SM_SBUF);

    // ---- phase A: thresholded ordered keys ----
    const float* cf = conf + (size_t)b * NA;
    for (int i = t; i < NA; i += 1024) {
        float c = cf[i];
        float cm = (c > 0.25f) ? c : -1.0f;
        ob[i] = ord_bits(cm);
    }
    if (t == 0) { s_prefix = 0; s_k = PRE_TOPK; s_cnt = 0; s_done = 0; }
    if (t < 16) s_supp[t] = 0;
    sbuf[t] = 0;
    __syncthreads();

    // radix-select exact rank-1000 key (keys unique: index embedded)
    for (int pass = 0; pass < 8; ++pass) {
        int shift = 56 - 8 * pass;
        if (t < 256) hist[t] = 0;
        __syncthreads();
        uint64_t prefix = s_prefix;
        int k = s_k;
        for (int i = t; i < NA; i += 1024) {
            uint64_t key = ((uint64_t)ob[i] << 32) | (uint64_t)(0xFFFFFFFFu - (uint32_t)i);
            bool match = (pass == 0) || (((key ^ prefix) >> (64 - 8 * pass)) == 0);
            if (match) atomicAdd(&hist[(uint32_t)(key >> shift) & 255u], 1u);
        }
        __syncthreads();
        if (t < 64) {   // wave-0 suffix-scan digit selection
            uint32_t h0 = hist[4 * t + 0], h1 = hist[4 * t + 1];
            uint32_t h2 = hist[4 * t + 2], h3 = hist[4 * t + 3];
            uint32_t part = h0 + h1 + h2 + h3;
            uint32_t s = part;
            #pragma unroll
            for (int off = 1; off < 64; off <<= 1) {
                uint32_t v = __shfl_down(s, off);
                if (t + off < 64) s += v;
            }
            uint32_t cb3 = s - part;
            uint32_t cb2 = cb3 + h3;
            uint32_t cb1 = cb2 + h2;
            uint32_t cb0 = cb1 + h1;
            uint32_t ku = (uint32_t)k;
            if (cb3 < ku && ku <= cb3 + h3) { s_k = k - (int)cb3; s_prefix = prefix | ((uint64_t)(uint32_t)(4 * t + 3) << shift); }
            if (cb2 < ku && ku <= cb2 + h2) { s_k = k - (int)cb2; s_prefix = prefix | ((uint64_t)(uint32_t)(4 * t + 2) << shift); }
            if (cb1 < ku && ku <= cb1 + h1) { s_k = k - (int)cb1; s_prefix = prefix | ((uint64_t)(uint32_t)(4 * t + 1) << shift); }
            if (cb0 < ku && ku <= cb0 + h0) { s_k = k - (int)cb0; s_prefix = prefix | ((uint64_t)(uint32_t)(4 * t + 0) << shift); }
        }
        __syncthreads();
    }

    // compact keys >= K* (exactly 1000 by key uniqueness)
    uint64_t kstar = s_prefix;
    for (int i = t; i < NA; i += 1024) {
        uint64_t key = ((uint64_t)ob[i] << 32) | (uint64_t)(0xFFFFFFFFu - (uint32_t)i);
        if (key >= kstar) {
            int p = atomicAdd(&s_cnt, 1);
            if (p < 1024) sbuf[p] = key;
        }
    }
    __syncthreads();
    // s_cnt was the compaction cursor (==1000); walk needs it at 0.
    if (t == 0) s_cnt = 0;

    // bitonic sort 1024 descending by (conf, -index)
    for (int k = 2; k <= 1024; k <<= 1) {
        for (int j = k >> 1; j > 0; j >>= 1) {
            int ixj = t ^ j;
            if (ixj > t) {
                uint64_t A = sbuf[t], Bv = sbuf[ixj];
                bool descBlock = ((t & k) == 0);
                bool sw = descBlock ? (A < Bv) : (A > Bv);
                if (sw) { sbuf[t] = Bv; sbuf[ixj] = A; }
            }
            __syncthreads();
        }
    }

    // ---- phase B: boxes/scores to LDS (padded layout) ----
    float4* boxes = (float4*)smem;
    float*  sv    = (float*)(smem + SM_SV);
    uint64_t* mrows = (uint64_t*)(smem + SM_MROWS);
    int* kept = (int*)(smem + SM_KEPT);

    if (t < PRE_TOPK) {
        uint64_t key = sbuf[t];
        uint32_t u = (uint32_t)(key >> 32);
        uint32_t fb = (u & 0x80000000u) ? (u ^ 0x80000000u) : ~u;
        sv[t] = __uint_as_float(fb);
        int idx = (int)(0xFFFFFFFFu - (uint32_t)(key & 0xFFFFFFFFull));
        size_t g = (size_t)b * NA + idx;
        float4 bx = *(const float4*)(box + g * 4);
        float cx = bx.x, cy = bx.y, w = bx.z, h = bx.w;
        boxes[bslot(t)] = make_float4(cx - w * 0.5f, cy - h * 0.5f, cx + w * 0.5f, cy + h * 0.5f);
    }
    __syncthreads();

    // ---- chunked IoU-mask + sequential walk, early-exit at 100 keeps ----
    for (int c = 0; c < 8; ++c) {
        int base = c * CHUNK;
        for (int tt = t; tt < CHUNK * 16; tt += 1024) {
            int rl = tt >> 4, w = tt & 15;
            int row = base + rl;
            unsigned long long bits = 0;
            float4 bi = boxes[bslot(row)];
            float area_i = (bi.z - bi.x) * (bi.w - bi.y);
            int j0 = w * 64;
            #pragma unroll 4
            for (int jj = 0; jj < 64; ++jj) {
                int j = j0 + jj;
                if (j >= PRE_TOPK) break;
                if (j <= row) continue;
                float4 bj = boxes[bslot(j)];
                float lx = fmaxf(bi.x, bj.x), ly = fmaxf(bi.y, bj.y);
                float rx = fminf(bi.z, bj.z), ry = fminf(bi.w, bj.w);
                float iw = fmaxf(rx - lx, 0.f), ih = fmaxf(ry - ly, 0.f);
                float inter = iw * ih;
                float area_j = (bj.z - bj.x) * (bj.w - bj.y);
                float iou = inter / (area_i + area_j - inter + 1e-7f);
                if (iou > 0.45f) bits |= (1ull << jj);
            }
            mrows[tt] = bits;
        }
        __syncthreads();
        if (t < 64) {  // wave-0 sequential walk
            unsigned long long supp = (t < 16) ? s_supp[t] : 0ull;
            int cnt = s_cnt;
            int end = base + CHUNK;
            for (int i = base; i < end; ++i) {
                int wsel = i >> 6, bit = i & 63;
                int sbit = (int)((supp >> bit) & 1ull);
                sbit = __shfl(sbit, wsel);
                bool keep = (!sbit) && (sv[i] > 0.0f);
                if (keep) {
                    if (t < 16) supp |= mrows[(i - base) * 16 + t];
                    if (t == 0 && cnt < MAX_DET) kept[cnt] = i;
                    ++cnt;
                }
            }
            if (t < 16) s_supp[t] = supp;
            if (t == 0) { s_cnt = cnt; if (cnt >= MAX_DET) s_done = 1; }
        }
        __syncthreads();
        if (s_done) break;   // uniform: written before the barrier
    }

    // ---- emit ----
    int cnt = s_cnt; if (cnt > MAX_DET) cnt = MAX_DET;
    if (t == 0) out[b] = (float)cnt;                       // num_dets (B,1)
    if (t < MAX_DET) {
        bool valid = t < cnt;
        float bx0 = 0.f, bx1 = 0.f, bx2 = 0.f, bx3 = 0.f, sc = 0.f, cl = 0.f;
        if (valid) {
            int p = kept[t];
            float4 bb = boxes[bslot(p)];
            bx0 = bb.x; bx1 = bb.y; bx2 = bb.z; bx3 = bb.w;
            sc = sv[p];
            uint64_t key = sbuf[p];
            int idx = (int)(0xFFFFFFFFu - (uint32_t)(key & 0xFFFFFFFFull));
            cl = (float)clsid[(size_t)b * NA + idx];
        }
        size_t db = 32 + ((size_t)b * MAX_DET + t) * 4;
        out[db + 0] = bx0; out[db + 1] = bx1; out[db + 2] = bx2; out[db + 3] = bx3;
        out[32 + 12800 + (size_t)b * MAX_DET + t] = sc;    // det_scores
        out[32 + 16000 + (size_t)b * MAX_DET + t] = cl;    // det_classes
    }
}

// ---------------- launch ----------------
extern "C" void kernel_launch(void* const* d_in, const int* in_sizes, int n_in,
                              void* d_out, int out_size, void* d_ws, size_t ws_size,
                              hipStream_t stream)
{
    const float* p3 = (const float*)d_in[0];
    const float* p4 = (const float*)d_in[1];
    const float* p5 = (const float*)d_in[2];
    float* out = (float*)d_out;

    char* ws = (char*)d_ws;
    size_t off_conf = 0;
    size_t off_cls  = off_conf + (size_t)NB * NA * 4;
    size_t off_box  = off_cls  + (size_t)NB * NA * 4;        // 16B-aligned

    float* conf  = (float*)(ws + off_conf);
    int*   clsid = (int*)(ws + off_cls);
    float* box   = (float*)(ws + off_box);

    k_decode<<<1050, 256, 0, stream>>>(p3, p4, p5, conf, clsid, box);
    k_post<<<NB, 1024, 0, stream>>>(conf, box, clsid, out);
}

// Round 6
// 144.228 us; speedup vs baseline: 1.3393x; 1.2002x over previous
//
#include <hip/hip_runtime.h>
#include <math.h>

#define NCLS 80
#define NA 8400
#define NB 32
#define NO 144
#define PRE_TOPK 1000
#define MAX_DET 100

// ---------------- Kernel 1: decode (DFL + max-logit sigmoid) ----------------
template<int HW, int WDIM, int S>
__device__ __forceinline__ void decode_store(
    const float* __restrict__ src, int g, int aoff,
    float* __restrict__ conf, int* __restrict__ clsid, float* __restrict__ box)
{
    int b = g / HW;
    int pos = g - b * HW;
    float ax = (float)(pos % WDIM) + 0.5f;
    float ay = (float)(pos / WDIM) + 0.5f;
    const float* base = src + (size_t)b * (NO * HW) + pos;

    float dist[4];
    #pragma unroll
    for (int s4 = 0; s4 < 4; ++s4) {
        float v[16];
        #pragma unroll
        for (int r = 0; r < 16; ++r) v[r] = base[(size_t)(s4 * 16 + r) * HW];
        float mm = v[0];
        #pragma unroll
        for (int r = 1; r < 16; ++r) mm = fmaxf(mm, v[r]);
        float sum = 0.f;
        #pragma unroll
        for (int r = 0; r < 16; ++r) { v[r] = __expf(v[r] - mm); sum += v[r]; }
        float inv = 1.0f / sum;
        float d = 0.f;
        #pragma unroll
        for (int r = 1; r < 16; ++r) d += (v[r] * inv) * (float)r;
        dist[s4] = d;
    }

    float best = -INFINITY; int bid = 0;
    #pragma unroll
    for (int ch = 0; ch < 4; ++ch) {
        float vc[20];
        #pragma unroll
        for (int c = 0; c < 20; ++c) vc[c] = base[(size_t)(64 + ch * 20 + c) * HW];
        float m = vc[0]; int ii = 0;
        #pragma unroll
        for (int c = 1; c < 20; ++c) if (vc[c] > m) { m = vc[c]; ii = c; }
        if (m > best) { best = m; bid = ch * 20 + ii; }
    }
    float conf_v = 1.0f / (1.0f + __expf(-best));

    float x1 = ax - dist[0], y1 = ay - dist[1];
    float x2 = ax + dist[2], y2 = ay + dist[3];
    float cx = ((x1 + x2) * 0.5f) * (float)S;
    float cy = ((y1 + y2) * 0.5f) * (float)S;
    float w  = (x2 - x1) * (float)S;
    float h  = (y2 - y1) * (float)S;

    size_t gid = (size_t)b * NA + aoff + pos;
    conf[gid]  = conf_v;
    clsid[gid] = bid;
    *(float4*)(box + gid * 4) = make_float4(cx, cy, w, h);
}

__global__ __launch_bounds__(256) void k_decode(
    const float* __restrict__ p3, const float* __restrict__ p4, const float* __restrict__ p5,
    float* __restrict__ conf, int* __restrict__ clsid, float* __restrict__ box)
{
    int blk = blockIdx.x;
    int t = threadIdx.x;
    if (blk < 800) {
        int g = blk * 256 + t;
        decode_store<6400, 80, 8>(p3, g, 0, conf, clsid, box);
    } else if (blk < 1000) {
        int g = (blk - 800) * 256 + t;
        decode_store<1600, 40, 16>(p4, g, 6400, conf, clsid, box);
    } else {
        int g = (blk - 1000) * 256 + t;
        decode_store<400, 20, 32>(p5, g, 8000, conf, clsid, box);
    }
}

// ---------------- Kernel 2: exact stable top-1000 per batch ----------------
__device__ __forceinline__ uint32_t ord_bits(float f) {
    uint32_t u = __float_as_uint(f);
    return (u & 0x80000000u) ? ~u : (u | 0x80000000u);
}

__global__ __launch_bounds__(1024) void k_select(
    const float* __restrict__ conf, const float* __restrict__ box, const int* __restrict__ clsid,
    float* __restrict__ topv, float* __restrict__ bxyxy, int* __restrict__ topcls)
{
    int b = blockIdx.x;
    int t = threadIdx.x;
    int lane = t & 63;

    __shared__ uint32_t ob[NA];          // 33.6 KB
    __shared__ uint32_t hist[256];
    __shared__ uint64_t sbuf[1024];      // 8 KB
    __shared__ uint64_t s_prefix;
    __shared__ int s_k;
    __shared__ int s_cnt;

    const float* cf = conf + (size_t)b * NA;
    for (int i = t; i < NA; i += 1024) {
        float c = cf[i];
        float cm = (c > 0.25f) ? c : -1.0f;
        ob[i] = ord_bits(cm);
    }
    if (t == 0) { s_prefix = 0; s_k = PRE_TOPK; s_cnt = 0; }
    sbuf[t] = 0;
    __syncthreads();

    // radix-select exact rank-1000 key. Histogram atomics are wave-aggregated:
    // ballot-partition lanes by digit (8 ballots), lowest lane adds popcount.
    // Kills the pass-0 same-bin serialization (conf values share a top byte).
    for (int pass = 0; pass < 8; ++pass) {
        int shift = 56 - 8 * pass;
        if (t < 256) hist[t] = 0;
        __syncthreads();
        uint64_t prefix = s_prefix;
        int k = s_k;
        for (int i = t; i < NA; i += 1024) {
            uint64_t key = ((uint64_t)ob[i] << 32) | (uint64_t)(0xFFFFFFFFu - (uint32_t)i);
            bool match = (pass == 0) || (((key ^ prefix) >> (64 - 8 * pass)) == 0);
            uint32_t d = (uint32_t)(key >> shift) & 255u;
            if (match) {
                uint64_t m = __ballot(1);     // active (matching) lanes
                #pragma unroll
                for (int bb = 0; bb < 8; ++bb) {
                    uint64_t bal = __ballot((d >> bb) & 1u);
                    m &= ((d >> bb) & 1u) ? bal : ~bal;
                }
                if ((m & ((1ull << lane) - 1ull)) == 0ull)     // lowest lane of digit-group
                    atomicAdd(&hist[d], (uint32_t)__popcll(m));
            }
        }
        __syncthreads();
        if (t < 64) {   // wave-0 suffix-scan digit selection
            uint32_t h0 = hist[4 * t + 0], h1 = hist[4 * t + 1];
            uint32_t h2 = hist[4 * t + 2], h3 = hist[4 * t + 3];
            uint32_t part = h0 + h1 + h2 + h3;
            uint32_t s = part;
            #pragma unroll
            for (int off = 1; off < 64; off <<= 1) {
                uint32_t v = __shfl_down(s, off);
                if (t + off < 64) s += v;
            }
            uint32_t cb3 = s - part;
            uint32_t cb2 = cb3 + h3;
            uint32_t cb1 = cb2 + h2;
            uint32_t cb0 = cb1 + h1;
            uint32_t ku = (uint32_t)k;
            if (cb3 < ku && ku <= cb3 + h3) { s_k = k - (int)cb3; s_prefix = prefix | ((uint64_t)(uint32_t)(4 * t + 3) << shift); }
            if (cb2 < ku && ku <= cb2 + h2) { s_k = k - (int)cb2; s_prefix = prefix | ((uint64_t)(uint32_t)(4 * t + 2) << shift); }
            if (cb1 < ku && ku <= cb1 + h1) { s_k = k - (int)cb1; s_prefix = prefix | ((uint64_t)(uint32_t)(4 * t + 1) << shift); }
            if (cb0 < ku && ku <= cb0 + h0) { s_k = k - (int)cb0; s_prefix = prefix | ((uint64_t)(uint32_t)(4 * t + 0) << shift); }
        }
        __syncthreads();
    }

    // compact keys >= K* (exactly 1000 by key uniqueness)
    uint64_t kstar = s_prefix;
    for (int i = t; i < NA; i += 1024) {
        uint64_t key = ((uint64_t)ob[i] << 32) | (uint64_t)(0xFFFFFFFFu - (uint32_t)i);
        if (key >= kstar) {
            int p = atomicAdd(&s_cnt, 1);
            if (p < 1024) sbuf[p] = key;
        }
    }
    __syncthreads();

    // bitonic sort 1024 descending by (conf, -index)
    for (int k = 2; k <= 1024; k <<= 1) {
        for (int j = k >> 1; j > 0; j >>= 1) {
            int ixj = t ^ j;
            if (ixj > t) {
                uint64_t A = sbuf[t], Bv = sbuf[ixj];
                bool descBlock = ((t & k) == 0);
                bool sw = descBlock ? (A < Bv) : (A > Bv);
                if (sw) { sbuf[t] = Bv; sbuf[ixj] = A; }
            }
            __syncthreads();
        }
    }

    if (t < PRE_TOPK) {
        uint64_t key = sbuf[t];
        uint32_t u = (uint32_t)(key >> 32);
        uint32_t fb = (u & 0x80000000u) ? (u ^ 0x80000000u) : ~u;
        float val = __uint_as_float(fb);
        int idx = (int)(0xFFFFFFFFu - (uint32_t)(key & 0xFFFFFFFFull));
        size_t g = (size_t)b * NA + idx;
        float4 bx = *(const float4*)(box + g * 4);
        float cx = bx.x, cy = bx.y, w = bx.z, h = bx.w;
        size_t o = (size_t)b * PRE_TOPK + t;
        topv[o] = val;
        *(float4*)(bxyxy + o * 4) = make_float4(cx - w * 0.5f, cy - h * 0.5f,
                                                cx + w * 0.5f, cy + h * 0.5f);
        topcls[o] = clsid[g];
    }
}

// ---------------- Kernel 3: pairwise IoU bitmask (full GPU) ----------------
__device__ __forceinline__ int bslot(int j) { return j + (j >> 6); }

__global__ __launch_bounds__(256) void k_iou(
    const float* __restrict__ bxyxy, unsigned long long* __restrict__ mask)
{
    __shared__ float4 boxes[PRE_TOPK + 16];   // padded: lane stride 65 float4 -> 2-way (free)
    int b = blockIdx.y;
    int t = threadIdx.x;
    const float4* bp = (const float4*)(bxyxy + (size_t)b * PRE_TOPK * 4);
    for (int i = t; i < PRE_TOPK; i += 256) boxes[bslot(i)] = bp[i];
    __syncthreads();

    int r_local = t >> 4, w = t & 15;
    int row = blockIdx.x * 16 + r_local;
    if (row >= PRE_TOPK) return;

    float4 bi = boxes[bslot(row)];
    float area_i = (bi.z - bi.x) * (bi.w - bi.y);
    unsigned long long bits = 0;
    int j0 = w * 64;
    #pragma unroll 4
    for (int jj = 0; jj < 64; ++jj) {
        int j = j0 + jj;
        if (j >= PRE_TOPK) break;
        if (j <= row) continue;
        float4 bj = boxes[bslot(j)];
        float lx = fmaxf(bi.x, bj.x), ly = fmaxf(bi.y, bj.y);
        float rx = fminf(bi.z, bj.z), ry = fminf(bi.w, bj.w);
        float iw = fmaxf(rx - lx, 0.f), ih = fmaxf(ry - ly, 0.f);
        float inter = iw * ih;
        float area_j = (bj.z - bj.x) * (bj.w - bj.y);
        float iou = inter / (area_i + area_j - inter + 1e-7f);
        if (iou > 0.45f) bits |= (1ull << jj);
    }
    mask[((size_t)b * PRE_TOPK + row) * 16 + w] = bits;
}

// ---------------- Kernel 4: leader-jump NMS walk + emit ----------------
// Full mask staged to LDS (128 KB), then one iteration PER KEPT box (<=100):
// OR leader's row into supp, bit-scan + shfl-min for the next unsuppressed
// candidate. Identical semantics to the sequential scan: every unsuppressed
// valid candidate is a leader, visited in increasing rank order.
__global__ __launch_bounds__(1024) void k_nms(
    const unsigned long long* __restrict__ mask, const float* __restrict__ topv,
    const float* __restrict__ bxyxy, const int* __restrict__ topcls,
    float* __restrict__ out)
{
    int b = blockIdx.x;
    int t = threadIdx.x;

    __shared__ __align__(16) unsigned long long smask[PRE_TOPK * 16];  // 128 KB
    __shared__ float sv[PRE_TOPK];
    __shared__ unsigned long long s_valid[16];
    __shared__ int kept[MAX_DET];
    __shared__ int s_cnt;

    // stage scores + full mask (L2-resident, coalesced 16B)
    for (int i = t; i < PRE_TOPK; i += 1024) sv[i] = topv[(size_t)b * PRE_TOPK + i];
    {
        const ulonglong2* src = (const ulonglong2*)(mask + (size_t)b * PRE_TOPK * 16);
        ulonglong2* dst = (ulonglong2*)smask;
        for (int i = t; i < PRE_TOPK * 8; i += 1024) dst[i] = src[i];
    }
    __syncthreads();

    // validity bitmap: wave w's ballot over lanes = word w (scores sorted desc)
    {
        bool pred = (t < PRE_TOPK) && (sv[t] > 0.0f);
        unsigned long long bal = __ballot(pred);
        if ((t & 63) == 0) s_valid[t >> 6] = bal;
    }
    __syncthreads();

    if (t < 64) {   // wave 0: leader-jump walk
        int w = t;
        unsigned long long supp = 0;
        unsigned long long valid = (w < 16) ? s_valid[w] : 0ull;
        int base = w * 64;
        int cur = -1;
        int cnt = 0;
        while (cnt < MAX_DET) {
            // candidate bits: valid, unsuppressed, index > cur
            unsigned long long gt;
            if (cur < base)            gt = ~0ull;
            else if (cur - base >= 63) gt = 0ull;
            else                       gt = (~0ull) << (cur - base + 1);
            unsigned long long cand = valid & ~supp & gt;
            int idx = cand ? (base + __builtin_ctzll(cand)) : 0x7FFFFFFF;
            #pragma unroll
            for (int off = 8; off >= 1; off >>= 1) {
                int o = __shfl_xor(idx, off);
                idx = (o < idx) ? o : idx;
            }
            int nxt = __shfl(idx, 0);
            if (nxt == 0x7FFFFFFF) break;
            if (t == 0) kept[cnt] = nxt;
            ++cnt;
            if (w < 16) supp |= smask[nxt * 16 + w];
            cur = nxt;
        }
        if (t == 0) s_cnt = cnt;
    }
    __syncthreads();

    // emit
    int cnt = s_cnt; if (cnt > MAX_DET) cnt = MAX_DET;
    if (t == 0) out[b] = (float)cnt;                       // num_dets (B,1)
    if (t < MAX_DET) {
        bool valid = t < cnt;
        float bx0 = 0.f, bx1 = 0.f, bx2 = 0.f, bx3 = 0.f, sc = 0.f, cl = 0.f;
        if (valid) {
            int p = kept[t];
            size_t o = (size_t)b * PRE_TOPK + p;
            float4 bb = *(const float4*)(bxyxy + o * 4);
            bx0 = bb.x; bx1 = bb.y; bx2 = bb.z; bx3 = bb.w;
            sc = sv[p];
            cl = (float)topcls[o];
        }
        size_t db = 32 + ((size_t)b * MAX_DET + t) * 4;
        out[db + 0] = bx0; out[db + 1] = bx1; out[db + 2] = bx2; out[db + 3] = bx3;
        out[32 + 12800 + (size_t)b * MAX_DET + t] = sc;    // det_scores
        out[32 + 16000 + (size_t)b * MAX_DET + t] = cl;    // det_classes
    }
}

// ---------------- launch ----------------
extern "C" void kernel_launch(void* const* d_in, const int* in_sizes, int n_in,
                              void* d_out, int out_size, void* d_ws, size_t ws_size,
                              hipStream_t stream)
{
    const float* p3 = (const float*)d_in[0];
    const float* p4 = (const float*)d_in[1];
    const float* p5 = (const float*)d_in[2];
    float* out = (float*)d_out;

    char* ws = (char*)d_ws;
    size_t off_mask = 0;                                       // 32*1000*16*8 = 4,096,000
    size_t off_conf = off_mask + (size_t)NB * PRE_TOPK * 16 * 8;
    size_t off_cls  = off_conf + (size_t)NB * NA * 4;
    size_t off_box  = off_cls  + (size_t)NB * NA * 4;
    size_t off_topv = off_box  + (size_t)NB * NA * 4 * 4;
    size_t off_topc = off_topv + (size_t)NB * PRE_TOPK * 4;
    size_t off_bx   = off_topc + (size_t)NB * PRE_TOPK * 4;

    unsigned long long* mask = (unsigned long long*)(ws + off_mask);
    float* conf   = (float*)(ws + off_conf);
    int*   clsid  = (int*)(ws + off_cls);
    float* box    = (float*)(ws + off_box);
    float* topv   = (float*)(ws + off_topv);
    int*   topcls = (int*)(ws + off_topc);
    float* bxyxy  = (float*)(ws + off_bx);

    k_decode<<<1050, 256, 0, stream>>>(p3, p4, p5, conf, clsid, box);
    k_select<<<NB, 1024, 0, stream>>>(conf, box, clsid, topv, bxyxy, topcls);
    k_iou<<<dim3((PRE_TOPK + 15) / 16, NB), 256, 0, stream>>>(bxyxy, mask);
    k_nms<<<NB, 1024, 0, stream>>>(mask, topv, bxyxy, topcls, out);
}